// Round 1
// baseline (174.739 us; speedup 1.0000x reference)
//
#include <hip/hip_runtime.h>

#define N 1024
#define H 256
#define EH 128

__device__ __forceinline__ float fast_silu(float x) {
    // x * sigmoid(x) = x * rcp(1 + exp2(-log2e * x))
    float u = __builtin_amdgcn_exp2f(x * -1.44269504088896340736f);
    return x * __builtin_amdgcn_rcpf(1.0f + u);
}

// ---------------- K1: node MLP + src/dst/ns + edge-weight prepack ----------------
// grid 256 blocks x 256 threads, 4 nodes per block
__global__ __launch_bounds__(256) void k_node(
    const float* __restrict__ h, const float* __restrict__ dl, const float* __restrict__ temb,
    const float* __restrict__ np1_w, const float* __restrict__ np1_b,
    const float* __restrict__ np2_w, const float* __restrict__ np2_b,
    const float* __restrict__ src_w, const float* __restrict__ src_b,
    const float* __restrict__ dst_w, const float* __restrict__ dst_b,
    const float* __restrict__ ns_w, const float* __restrict__ ns_b,
    const float* __restrict__ eg1_w, const float* __restrict__ eg1_b,
    const float* __restrict__ eg2_w,
    float* __restrict__ nh, float* __restrict__ srcv, float* __restrict__ dstv,
    float* __restrict__ nsv, float* __restrict__ wpA, float* __restrict__ wpB)
{
    const int TILE = 4;
    __shared__ float feat[TILE][264];
    __shared__ float red[TILE][3][4];
    const int tid = threadIdx.x;
    const int blk = blockIdx.x;
    const int n0 = blk * TILE;

    // block 0: pre-scale edge MLP weights: t2 = -log2e * preact, w2' = -ln2 * w2
    if (blk == 0 && tid < EH) {
        const float NL2E = -1.44269504088896340736f;
        const float NLN2 = -0.69314718055994530942f;
        float4 a;
        a.x = NL2E * eg1_w[0 * EH + tid];
        a.y = NL2E * eg1_w[1 * EH + tid];
        a.z = NL2E * eg1_w[2 * EH + tid];
        a.w = NL2E * eg1_w[3 * EH + tid];
        ((float4*)wpA)[tid] = a;
        float2 b;
        b.x = NL2E * eg1_b[tid];
        b.y = NLN2 * eg2_w[tid];
        ((float2*)wpB)[tid] = b;
    }

    // stage features [h | delta_local | t_emb | pad]
    for (int idx = tid; idx < TILE * 264; idx += 256) {
        int t = idx / 264, i = idx % 264;
        int n = n0 + t;
        float v = 0.0f;
        if (i < H)            v = h[n * H + i];
        else if (i < H + 3)   v = dl[n * 3 + (i - H)];
        else if (i < H + 6)   v = temb[n * 3 + (i - H - 3)];
        feat[t][i] = v;
    }
    __syncthreads();

    const int j = tid;
    float acc[TILE];
#pragma unroll
    for (int t = 0; t < TILE; t++) acc[t] = np1_b[j];
    int i = 0;
    for (; i + 4 <= 262; i += 4) {
        float w0 = np1_w[(i + 0) * H + j];
        float w1 = np1_w[(i + 1) * H + j];
        float w2 = np1_w[(i + 2) * H + j];
        float w3 = np1_w[(i + 3) * H + j];
#pragma unroll
        for (int t = 0; t < TILE; t++) {
            float4 f = *(const float4*)&feat[t][i];
            acc[t] = fmaf(f.x, w0, fmaf(f.y, w1, fmaf(f.z, w2, fmaf(f.w, w3, acc[t]))));
        }
    }
    for (; i < 262; i++) {
        float w = np1_w[i * H + j];
#pragma unroll
        for (int t = 0; t < TILE; t++) acc[t] = fmaf(feat[t][i], w, acc[t]);
    }
    __syncthreads();
#pragma unroll
    for (int t = 0; t < TILE; t++) feat[t][j] = fast_silu(acc[t]);
    __syncthreads();

    // L2: 256 -> 256
#pragma unroll
    for (int t = 0; t < TILE; t++) acc[t] = np2_b[j];
    for (int i2 = 0; i2 < H; i2 += 4) {
        float w0 = np2_w[(i2 + 0) * H + j];
        float w1 = np2_w[(i2 + 1) * H + j];
        float w2 = np2_w[(i2 + 2) * H + j];
        float w3 = np2_w[(i2 + 3) * H + j];
#pragma unroll
        for (int t = 0; t < TILE; t++) {
            float4 f = *(const float4*)&feat[t][i2];
            acc[t] = fmaf(f.x, w0, fmaf(f.y, w1, fmaf(f.z, w2, fmaf(f.w, w3, acc[t]))));
        }
    }
    float hj[TILE];
#pragma unroll
    for (int t = 0; t < TILE; t++) {
        hj[t] = fast_silu(acc[t]);
        nh[(n0 + t) * H + j] = hj[t];
    }

    // src/dst/ns GEMVs via block reduction
    float wsc = src_w[j], wdc = dst_w[j], wnc = ns_w[j];
    const int lane = tid & 63, wv = tid >> 6;
#pragma unroll
    for (int t = 0; t < TILE; t++) {
        float ps = hj[t] * wsc, pd = hj[t] * wdc, pn = hj[t] * wnc;
#pragma unroll
        for (int o = 32; o > 0; o >>= 1) {
            ps += __shfl_down(ps, o);
            pd += __shfl_down(pd, o);
            pn += __shfl_down(pn, o);
        }
        if (lane == 0) { red[t][0][wv] = ps; red[t][1][wv] = pd; red[t][2][wv] = pn; }
    }
    __syncthreads();
    if (tid < TILE) {
        int t = tid;
        float s  = red[t][0][0] + red[t][0][1] + red[t][0][2] + red[t][0][3] + src_b[0];
        float d  = red[t][1][0] + red[t][1][1] + red[t][1][2] + red[t][1][3] + dst_b[0];
        float nl = red[t][2][0] + red[t][2][1] + red[t][2][2] + red[t][2][3] + ns_b[0];
        srcv[n0 + t] = s;
        dstv[n0 + t] = d;
        nsv[n0 + t]  = __builtin_amdgcn_rcpf(1.0f + __builtin_amdgcn_exp2f(nl * -1.44269504088896340736f));
    }
}

// ---------------- K2: per-row edge MLP + softmax + messages ----------------
// grid 1024 blocks (one per n) x 256 threads, 4 edges per thread
__global__ __launch_bounds__(256) void k_edge(
    const float* __restrict__ x, const float* __restrict__ frames,
    const float* __restrict__ srcv, const float* __restrict__ dstv,
    const float* __restrict__ nsv,
    const float* __restrict__ wpA, const float* __restrict__ wpB,
    const float* __restrict__ eg2_b, float* __restrict__ msg)
{
    __shared__ float4 WA[EH];
    __shared__ float2 WB[EH];
    __shared__ float rmax[4];
    __shared__ float rsum[4];
    __shared__ float rmsg[3][4];
    const int tid = threadIdx.x;
    const int n = blockIdx.x;

    if (tid < EH) {
        WA[tid] = ((const float4*)wpA)[tid];
        WB[tid] = ((const float2*)wpB)[tid];
    }

    float F[9];
#pragma unroll
    for (int q = 0; q < 9; q++) F[q] = frames[n * 9 + q];
    const float xn0 = x[n * 3 + 0], xn1 = x[n * 3 + 1], xn2 = x[n * 3 + 2];
    const float src_n = srcv[n];
    const float eg2b = eg2_b[0];
    __syncthreads();

    float rl[4][3], dist[4], dstm[4], nsm[4];
#pragma unroll
    for (int e = 0; e < 4; e++) {
        int m = tid + e * 256;
        float rx = x[m * 3 + 0] - xn0;
        float ry = x[m * 3 + 1] - xn1;
        float rz = x[m * 3 + 2] - xn2;
        // rel_local[i] = sum_j frames[n,j,i] * rel[j]
        float r0 = F[0] * rx + F[3] * ry + F[6] * rz;
        float r1 = F[1] * rx + F[4] * ry + F[7] * rz;
        float r2 = F[2] * rx + F[5] * ry + F[8] * rz;
        rl[e][0] = r0; rl[e][1] = r1; rl[e][2] = r2;
        dist[e] = sqrtf(r0 * r0 + r1 * r1 + r2 * r2);
        dstm[e] = dstv[m];
        nsm[e]  = nsv[m];
    }

    float acc[4] = {0.f, 0.f, 0.f, 0.f};
#pragma unroll 4
    for (int k = 0; k < EH; k++) {
        float4 w = WA[k];
        float2 c = WB[k];
#pragma unroll
        for (int e = 0; e < 4; e++) {
            // t2 = -log2e * preact (weights pre-scaled)
            float t2 = fmaf(rl[e][0], w.x, fmaf(rl[e][1], w.y, fmaf(rl[e][2], w.z, fmaf(dist[e], w.w, c.x))));
            float r = __builtin_amdgcn_rcpf(1.0f + __builtin_amdgcn_exp2f(t2));
            acc[e] = fmaf(t2 * r, c.y, acc[e]);   // c.y = -ln2 * eg2_w -> silu(t)*eg2_w
        }
    }

    float lg[4];
#pragma unroll
    for (int e = 0; e < 4; e++) {
        int m = tid + e * 256;
        lg[e] = (m == n) ? -10000.0f : (src_n + dstm[e] + acc[e] + eg2b);
    }

    const int lane = tid & 63, wv = tid >> 6;
    // block max
    float mx = fmaxf(fmaxf(lg[0], lg[1]), fmaxf(lg[2], lg[3]));
#pragma unroll
    for (int o = 32; o > 0; o >>= 1) mx = fmaxf(mx, __shfl_down(mx, o));
    if (lane == 0) rmax[wv] = mx;
    __syncthreads();
    mx = fmaxf(fmaxf(rmax[0], rmax[1]), fmaxf(rmax[2], rmax[3]));

    // exp + sum (diag underflows to exactly 0)
    float p[4]; float s = 0.f;
#pragma unroll
    for (int e = 0; e < 4; e++) {
        p[e] = __builtin_amdgcn_exp2f((lg[e] - mx) * 1.44269504088896340736f);
        s += p[e];
    }
#pragma unroll
    for (int o = 32; o > 0; o >>= 1) s += __shfl_down(s, o);
    if (lane == 0) rsum[wv] = s;
    __syncthreads();
    float S = rsum[0] + rsum[1] + rsum[2] + rsum[3];
    float inv = 1.0f / S;

    // messages: sum_m attn * ns[m] * rel_local
    float a0 = 0.f, a1 = 0.f, a2 = 0.f;
#pragma unroll
    for (int e = 0; e < 4; e++) {
        float w = p[e] * inv * nsm[e];
        a0 = fmaf(w, rl[e][0], a0);
        a1 = fmaf(w, rl[e][1], a1);
        a2 = fmaf(w, rl[e][2], a2);
    }
#pragma unroll
    for (int o = 32; o > 0; o >>= 1) {
        a0 += __shfl_down(a0, o);
        a1 += __shfl_down(a1, o);
        a2 += __shfl_down(a2, o);
    }
    if (lane == 0) { rmsg[0][wv] = a0; rmsg[1][wv] = a1; rmsg[2][wv] = a2; }
    __syncthreads();
    if (tid < 3) {
        msg[n * 3 + tid] = rmsg[tid][0] + rmsg[tid][1] + rmsg[tid][2] + rmsg[tid][3];
    }
}

// ---------------- K3: output MLP ----------------
// grid 256 blocks x 256 threads, 4 nodes per block
__global__ __launch_bounds__(256) void k_out(
    const float* __restrict__ nh, const float* __restrict__ dl, const float* __restrict__ msg,
    const float* __restrict__ out1_w, const float* __restrict__ out1_b,
    const float* __restrict__ out2_w, const float* __restrict__ out2_b,
    float* __restrict__ out)
{
    const int TILE = 4;
    __shared__ float feat[TILE][264];
    __shared__ float red[TILE][3][4];
    const int tid = threadIdx.x;
    const int blk = blockIdx.x;
    const int n0 = blk * TILE;

    for (int idx = tid; idx < TILE * 264; idx += 256) {
        int t = idx / 264, i = idx % 264;
        int n = n0 + t;
        float v = 0.0f;
        if (i < H)          v = nh[n * H + i];
        else if (i < H + 3) v = dl[n * 3 + (i - H)];
        else if (i < H + 6) v = msg[n * 3 + (i - H - 3)];
        feat[t][i] = v;
    }
    __syncthreads();

    const int j = tid;
    float acc[TILE];
#pragma unroll
    for (int t = 0; t < TILE; t++) acc[t] = out1_b[j];
    int i = 0;
    for (; i + 4 <= 262; i += 4) {
        float w0 = out1_w[(i + 0) * H + j];
        float w1 = out1_w[(i + 1) * H + j];
        float w2 = out1_w[(i + 2) * H + j];
        float w3 = out1_w[(i + 3) * H + j];
#pragma unroll
        for (int t = 0; t < TILE; t++) {
            float4 f = *(const float4*)&feat[t][i];
            acc[t] = fmaf(f.x, w0, fmaf(f.y, w1, fmaf(f.z, w2, fmaf(f.w, w3, acc[t]))));
        }
    }
    for (; i < 262; i++) {
        float w = out1_w[i * H + j];
#pragma unroll
        for (int t = 0; t < TILE; t++) acc[t] = fmaf(feat[t][i], w, acc[t]);
    }

    float hj[TILE];
#pragma unroll
    for (int t = 0; t < TILE; t++) hj[t] = fast_silu(acc[t]);

    // L2: 256 -> 3 via block reduction; out2_w is [256][3]
    float w0 = out2_w[j * 3 + 0], w1 = out2_w[j * 3 + 1], w2 = out2_w[j * 3 + 2];
    const int lane = tid & 63, wv = tid >> 6;
#pragma unroll
    for (int t = 0; t < TILE; t++) {
        float p0 = hj[t] * w0, p1 = hj[t] * w1, p2 = hj[t] * w2;
#pragma unroll
        for (int o = 32; o > 0; o >>= 1) {
            p0 += __shfl_down(p0, o);
            p1 += __shfl_down(p1, o);
            p2 += __shfl_down(p2, o);
        }
        if (lane == 0) { red[t][0][wv] = p0; red[t][1][wv] = p1; red[t][2][wv] = p2; }
    }
    __syncthreads();
    if (tid < TILE * 3) {
        int t = tid / 3, d = tid % 3;
        float v = red[t][d][0] + red[t][d][1] + red[t][d][2] + red[t][d][3] + out2_b[d];
        int n = n0 + t;
        out[n * 3 + d] = v + 0.25f * msg[n * 3 + d];
    }
}

extern "C" void kernel_launch(void* const* d_in, const int* in_sizes, int n_in,
                              void* d_out, int out_size, void* d_ws, size_t ws_size,
                              hipStream_t stream) {
    const float* h      = (const float*)d_in[0];
    const float* dl     = (const float*)d_in[1];
    const float* temb   = (const float*)d_in[2];
    const float* x      = (const float*)d_in[3];
    const float* fr     = (const float*)d_in[4];
    const float* np1_w  = (const float*)d_in[5];
    const float* np1_b  = (const float*)d_in[6];
    const float* np2_w  = (const float*)d_in[7];
    const float* np2_b  = (const float*)d_in[8];
    const float* src_w  = (const float*)d_in[9];
    const float* src_b  = (const float*)d_in[10];
    const float* dst_w  = (const float*)d_in[11];
    const float* dst_b  = (const float*)d_in[12];
    const float* ns_w   = (const float*)d_in[13];
    const float* ns_b   = (const float*)d_in[14];
    const float* eg1_w  = (const float*)d_in[15];
    const float* eg1_b  = (const float*)d_in[16];
    const float* eg2_w  = (const float*)d_in[17];
    const float* eg2_b  = (const float*)d_in[18];
    const float* out1_w = (const float*)d_in[19];
    const float* out1_b = (const float*)d_in[20];
    const float* out2_w = (const float*)d_in[21];
    const float* out2_b = (const float*)d_in[22];

    float* ws   = (float*)d_ws;
    float* nh   = ws;                   // 1024*256
    float* srcv = nh + 1024 * 256;      // 1024
    float* dstv = srcv + 1024;          // 1024
    float* nsv  = dstv + 1024;          // 1024
    float* msg  = nsv + 1024;           // 1024*3
    float* wpA  = msg + 1024 * 3;       // 128*4 (16B-aligned offset)
    float* wpB  = wpA + 512;            // 128*2

    k_node<<<256, 256, 0, stream>>>(h, dl, temb, np1_w, np1_b, np2_w, np2_b,
                                    src_w, src_b, dst_w, dst_b, ns_w, ns_b,
                                    eg1_w, eg1_b, eg2_w,
                                    nh, srcv, dstv, nsv, wpA, wpB);
    k_edge<<<1024, 256, 0, stream>>>(x, fr, srcv, dstv, nsv, wpA, wpB, eg2_b, msg);
    k_out<<<256, 256, 0, stream>>>(nh, dl, msg, out1_w, out1_b, out2_w, out2_b, (float*)d_out);
}

// Round 2
// 161.581 us; speedup vs baseline: 1.0814x; 1.0814x over previous
//
#include <hip/hip_runtime.h>

#define N 1024
#define H 256
#define EH 128

__device__ __forceinline__ float fast_silu(float x) {
    float u = __builtin_amdgcn_exp2f(x * -1.44269504088896340736f);
    return x * __builtin_amdgcn_rcpf(1.0f + u);
}

// ---------------- K1: node MLP + src/dst/ns + edge-weight prepack ----------------
// grid 256 blocks x 1024 threads; 4 nodes per block; reduction split across 4 segs
__global__ __launch_bounds__(1024) void k_node(
    const float* __restrict__ h, const float* __restrict__ dl, const float* __restrict__ temb,
    const float* __restrict__ np1_w, const float* __restrict__ np1_b,
    const float* __restrict__ np2_w, const float* __restrict__ np2_b,
    const float* __restrict__ src_w, const float* __restrict__ src_b,
    const float* __restrict__ dst_w, const float* __restrict__ dst_b,
    const float* __restrict__ ns_w, const float* __restrict__ ns_b,
    const float* __restrict__ eg1_w, const float* __restrict__ eg1_b,
    const float* __restrict__ eg2_w,
    float* __restrict__ nh, float* __restrict__ srcv, float* __restrict__ dstv,
    float* __restrict__ nsv, float* __restrict__ wpA, float* __restrict__ wpB)
{
    __shared__ float feat[4][264];
    __shared__ float sred[4][4][256];   // [tile][seg][j]
    __shared__ float gred[4][3][4];
    const int tid = threadIdx.x;
    const int j   = tid & 255;
    const int seg = tid >> 8;
    const int n0  = blockIdx.x * 4;

    // block 0: pre-scale edge MLP weights: t2 = -log2e * preact, w2' = -ln2 * w2
    if (blockIdx.x == 0 && tid < EH) {
        const float NL2E = -1.44269504088896340736f;
        const float NLN2 = -0.69314718055994530942f;
        float4 a;
        a.x = NL2E * eg1_w[0 * EH + tid];
        a.y = NL2E * eg1_w[1 * EH + tid];
        a.z = NL2E * eg1_w[2 * EH + tid];
        a.w = NL2E * eg1_w[3 * EH + tid];
        ((float4*)wpA)[tid] = a;
        float2 b;
        b.x = NL2E * eg1_b[tid];
        b.y = NLN2 * eg2_w[tid];
        ((float2*)wpB)[tid] = b;
    }

    // stage features [h | delta_local | t_emb | pad]
    for (int idx = tid; idx < 4 * 264; idx += 1024) {
        int t = idx / 264, i = idx % 264;
        int n = n0 + t;
        float v = 0.0f;
        if (i < H)            v = h[n * H + i];
        else if (i < H + 3)   v = dl[n * 3 + (i - H)];
        else if (i < H + 6)   v = temb[n * 3 + (i - H - 3)];
        feat[t][i] = v;
    }
    __syncthreads();

    // L1: 262 -> 256, seg s handles i in [66s, 66s+66) (last: 64)
    {
        float a0 = 0.f, a1 = 0.f, a2 = 0.f, a3 = 0.f;
        const int lo = seg * 66;
        const int hi = lo + ((seg == 3) ? 64 : 66);
        for (int i = lo; i < hi; i += 2) {
            float w0 = np1_w[i * H + j];
            float w1 = np1_w[(i + 1) * H + j];
            float2 f0 = *(const float2*)&feat[0][i];
            float2 f1 = *(const float2*)&feat[1][i];
            float2 f2 = *(const float2*)&feat[2][i];
            float2 f3 = *(const float2*)&feat[3][i];
            a0 = fmaf(f0.x, w0, fmaf(f0.y, w1, a0));
            a1 = fmaf(f1.x, w0, fmaf(f1.y, w1, a1));
            a2 = fmaf(f2.x, w0, fmaf(f2.y, w1, a2));
            a3 = fmaf(f3.x, w0, fmaf(f3.y, w1, a3));
        }
        sred[0][seg][j] = a0;
        sred[1][seg][j] = a1;
        sred[2][seg][j] = a2;
        sred[3][seg][j] = a3;
    }
    __syncthreads();
    // combine + SiLU; thread (seg,j) owns tile t=seg
    {
        float s = sred[seg][0][j] + sred[seg][1][j] + sred[seg][2][j] + sred[seg][3][j] + np1_b[j];
        float hv = fast_silu(s);
        feat[seg][j] = hv;   // safe: all L1 reads of feat completed before prior barrier
    }
    __syncthreads();

    // L2: 256 -> 256, seg s handles i in [64s, 64s+64)
    {
        float a0 = 0.f, a1 = 0.f, a2 = 0.f, a3 = 0.f;
        const int lo = seg * 64;
        for (int i = lo; i < lo + 64; i += 2) {
            float w0 = np2_w[i * H + j];
            float w1 = np2_w[(i + 1) * H + j];
            float2 f0 = *(const float2*)&feat[0][i];
            float2 f1 = *(const float2*)&feat[1][i];
            float2 f2 = *(const float2*)&feat[2][i];
            float2 f3 = *(const float2*)&feat[3][i];
            a0 = fmaf(f0.x, w0, fmaf(f0.y, w1, a0));
            a1 = fmaf(f1.x, w0, fmaf(f1.y, w1, a1));
            a2 = fmaf(f2.x, w0, fmaf(f2.y, w1, a2));
            a3 = fmaf(f3.x, w0, fmaf(f3.y, w1, a3));
        }
        sred[0][seg][j] = a0;
        sred[1][seg][j] = a1;
        sred[2][seg][j] = a2;
        sred[3][seg][j] = a3;
    }
    __syncthreads();

    float h2 = fast_silu(sred[seg][0][j] + sred[seg][1][j] + sred[seg][2][j] + sred[seg][3][j] + np2_b[j]);
    nh[(n0 + seg) * H + j] = h2;

    // src/dst/ns GEMVs: tile t=seg, reduce 256 j's (4 waves per seg)
    {
        float ps = h2 * src_w[j], pd = h2 * dst_w[j], pn = h2 * ns_w[j];
        const int lane = tid & 63, wvl = (tid >> 6) & 3;
#pragma unroll
        for (int o = 32; o > 0; o >>= 1) {
            ps += __shfl_down(ps, o);
            pd += __shfl_down(pd, o);
            pn += __shfl_down(pn, o);
        }
        if (lane == 0) { gred[seg][0][wvl] = ps; gred[seg][1][wvl] = pd; gred[seg][2][wvl] = pn; }
    }
    __syncthreads();
    if (tid < 4) {
        int t = tid;
        float s  = gred[t][0][0] + gred[t][0][1] + gred[t][0][2] + gred[t][0][3] + src_b[0];
        float d  = gred[t][1][0] + gred[t][1][1] + gred[t][1][2] + gred[t][1][3] + dst_b[0];
        float nl = gred[t][2][0] + gred[t][2][1] + gred[t][2][2] + gred[t][2][3] + ns_b[0];
        srcv[n0 + t] = s;
        dstv[n0 + t] = d;
        nsv[n0 + t]  = __builtin_amdgcn_rcpf(1.0f + __builtin_amdgcn_exp2f(nl * -1.44269504088896340736f));
    }
}

// ---------------- K2: per-row edge MLP + softmax + messages ----------------
// grid 1024 blocks (one per n) x 512 threads, 2 edges per thread -> 8 waves/SIMD
__global__ __launch_bounds__(512) void k_edge(
    const float* __restrict__ x, const float* __restrict__ frames,
    const float* __restrict__ srcv, const float* __restrict__ dstv,
    const float* __restrict__ nsv,
    const float* __restrict__ wpA, const float* __restrict__ wpB,
    const float* __restrict__ eg2_b, float* __restrict__ msg)
{
    __shared__ float4 WA[EH];
    __shared__ float2 WB[EH];
    __shared__ float rmax[8];
    __shared__ float rsum[8];
    __shared__ float rmsg[3][8];
    const int tid = threadIdx.x;
    const int n = blockIdx.x;

    if (tid < EH) {
        WA[tid] = ((const float4*)wpA)[tid];
        WB[tid] = ((const float2*)wpB)[tid];
    }

    float F[9];
#pragma unroll
    for (int q = 0; q < 9; q++) F[q] = frames[n * 9 + q];
    const float xn0 = x[n * 3 + 0], xn1 = x[n * 3 + 1], xn2 = x[n * 3 + 2];
    const float src_n = srcv[n];
    const float eg2b = eg2_b[0];
    __syncthreads();

    float rl[2][3], dist[2], dstm[2], nsm[2];
#pragma unroll
    for (int e = 0; e < 2; e++) {
        int m = tid + e * 512;
        float rx = x[m * 3 + 0] - xn0;
        float ry = x[m * 3 + 1] - xn1;
        float rz = x[m * 3 + 2] - xn2;
        float r0 = F[0] * rx + F[3] * ry + F[6] * rz;
        float r1 = F[1] * rx + F[4] * ry + F[7] * rz;
        float r2 = F[2] * rx + F[5] * ry + F[8] * rz;
        rl[e][0] = r0; rl[e][1] = r1; rl[e][2] = r2;
        dist[e] = sqrtf(r0 * r0 + r1 * r1 + r2 * r2);
        dstm[e] = dstv[m];
        nsm[e]  = nsv[m];
    }

    float acc[2] = {0.f, 0.f};
#pragma unroll 4
    for (int k = 0; k < EH; k++) {
        float4 w = WA[k];
        float2 c = WB[k];
#pragma unroll
        for (int e = 0; e < 2; e++) {
            float t2 = fmaf(rl[e][0], w.x, fmaf(rl[e][1], w.y, fmaf(rl[e][2], w.z, fmaf(dist[e], w.w, c.x))));
            float r = __builtin_amdgcn_rcpf(1.0f + __builtin_amdgcn_exp2f(t2));
            acc[e] = fmaf(t2 * r, c.y, acc[e]);
        }
    }

    float lg[2];
#pragma unroll
    for (int e = 0; e < 2; e++) {
        int m = tid + e * 512;
        lg[e] = (m == n) ? -10000.0f : (src_n + dstm[e] + acc[e] + eg2b);
    }

    const int lane = tid & 63, wv = tid >> 6;
    float mx = fmaxf(lg[0], lg[1]);
#pragma unroll
    for (int o = 32; o > 0; o >>= 1) mx = fmaxf(mx, __shfl_down(mx, o));
    if (lane == 0) rmax[wv] = mx;
    __syncthreads();
    mx = rmax[0];
#pragma unroll
    for (int q = 1; q < 8; q++) mx = fmaxf(mx, rmax[q]);

    float p[2]; float s = 0.f;
#pragma unroll
    for (int e = 0; e < 2; e++) {
        p[e] = __builtin_amdgcn_exp2f((lg[e] - mx) * 1.44269504088896340736f);
        s += p[e];
    }
#pragma unroll
    for (int o = 32; o > 0; o >>= 1) s += __shfl_down(s, o);
    if (lane == 0) rsum[wv] = s;
    __syncthreads();
    float S = rsum[0] + rsum[1] + rsum[2] + rsum[3] + rsum[4] + rsum[5] + rsum[6] + rsum[7];
    float inv = 1.0f / S;

    float a0 = 0.f, a1 = 0.f, a2 = 0.f;
#pragma unroll
    for (int e = 0; e < 2; e++) {
        float w = p[e] * inv * nsm[e];
        a0 = fmaf(w, rl[e][0], a0);
        a1 = fmaf(w, rl[e][1], a1);
        a2 = fmaf(w, rl[e][2], a2);
    }
#pragma unroll
    for (int o = 32; o > 0; o >>= 1) {
        a0 += __shfl_down(a0, o);
        a1 += __shfl_down(a1, o);
        a2 += __shfl_down(a2, o);
    }
    if (lane == 0) { rmsg[0][wv] = a0; rmsg[1][wv] = a1; rmsg[2][wv] = a2; }
    __syncthreads();
    if (tid < 3) {
        float v = 0.f;
#pragma unroll
        for (int q = 0; q < 8; q++) v += rmsg[tid][q];
        msg[n * 3 + tid] = v;
    }
}

// ---------------- K3: output MLP ----------------
// grid 256 blocks x 1024 threads; same seg-split structure as K1
__global__ __launch_bounds__(1024) void k_out(
    const float* __restrict__ nh, const float* __restrict__ dl, const float* __restrict__ msg,
    const float* __restrict__ out1_w, const float* __restrict__ out1_b,
    const float* __restrict__ out2_w, const float* __restrict__ out2_b,
    float* __restrict__ out)
{
    __shared__ float feat[4][264];
    __shared__ float sred[4][4][256];
    __shared__ float gred[4][3][4];
    const int tid = threadIdx.x;
    const int j   = tid & 255;
    const int seg = tid >> 8;
    const int n0  = blockIdx.x * 4;

    for (int idx = tid; idx < 4 * 264; idx += 1024) {
        int t = idx / 264, i = idx % 264;
        int n = n0 + t;
        float v = 0.0f;
        if (i < H)          v = nh[n * H + i];
        else if (i < H + 3) v = dl[n * 3 + (i - H)];
        else if (i < H + 6) v = msg[n * 3 + (i - H - 3)];
        feat[t][i] = v;
    }
    __syncthreads();

    // L1: 262 -> 256
    {
        float a0 = 0.f, a1 = 0.f, a2 = 0.f, a3 = 0.f;
        const int lo = seg * 66;
        const int hi = lo + ((seg == 3) ? 64 : 66);
        for (int i = lo; i < hi; i += 2) {
            float w0 = out1_w[i * H + j];
            float w1 = out1_w[(i + 1) * H + j];
            float2 f0 = *(const float2*)&feat[0][i];
            float2 f1 = *(const float2*)&feat[1][i];
            float2 f2 = *(const float2*)&feat[2][i];
            float2 f3 = *(const float2*)&feat[3][i];
            a0 = fmaf(f0.x, w0, fmaf(f0.y, w1, a0));
            a1 = fmaf(f1.x, w0, fmaf(f1.y, w1, a1));
            a2 = fmaf(f2.x, w0, fmaf(f2.y, w1, a2));
            a3 = fmaf(f3.x, w0, fmaf(f3.y, w1, a3));
        }
        sred[0][seg][j] = a0;
        sred[1][seg][j] = a1;
        sred[2][seg][j] = a2;
        sred[3][seg][j] = a3;
    }
    __syncthreads();

    // combine + SiLU; thread (seg,j) owns tile t=seg; then 256->3 reduction
    float hv = fast_silu(sred[seg][0][j] + sred[seg][1][j] + sred[seg][2][j] + sred[seg][3][j] + out1_b[j]);
    {
        float w0 = out2_w[j * 3 + 0], w1 = out2_w[j * 3 + 1], w2 = out2_w[j * 3 + 2];
        float p0 = hv * w0, p1 = hv * w1, p2 = hv * w2;
        const int lane = tid & 63, wvl = (tid >> 6) & 3;
#pragma unroll
        for (int o = 32; o > 0; o >>= 1) {
            p0 += __shfl_down(p0, o);
            p1 += __shfl_down(p1, o);
            p2 += __shfl_down(p2, o);
        }
        if (lane == 0) { gred[seg][0][wvl] = p0; gred[seg][1][wvl] = p1; gred[seg][2][wvl] = p2; }
    }
    __syncthreads();
    if (tid < 12) {
        int t = tid / 3, d = tid % 3;
        float v = gred[t][d][0] + gred[t][d][1] + gred[t][d][2] + gred[t][d][3] + out2_b[d];
        int n = n0 + t;
        out[n * 3 + d] = v + 0.25f * msg[n * 3 + d];
    }
}

extern "C" void kernel_launch(void* const* d_in, const int* in_sizes, int n_in,
                              void* d_out, int out_size, void* d_ws, size_t ws_size,
                              hipStream_t stream) {
    const float* h      = (const float*)d_in[0];
    const float* dl     = (const float*)d_in[1];
    const float* temb   = (const float*)d_in[2];
    const float* x      = (const float*)d_in[3];
    const float* fr     = (const float*)d_in[4];
    const float* np1_w  = (const float*)d_in[5];
    const float* np1_b  = (const float*)d_in[6];
    const float* np2_w  = (const float*)d_in[7];
    const float* np2_b  = (const float*)d_in[8];
    const float* src_w  = (const float*)d_in[9];
    const float* src_b  = (const float*)d_in[10];
    const float* dst_w  = (const float*)d_in[11];
    const float* dst_b  = (const float*)d_in[12];
    const float* ns_w   = (const float*)d_in[13];
    const float* ns_b   = (const float*)d_in[14];
    const float* eg1_w  = (const float*)d_in[15];
    const float* eg1_b  = (const float*)d_in[16];
    const float* eg2_w  = (const float*)d_in[17];
    const float* eg2_b  = (const float*)d_in[18];
    const float* out1_w = (const float*)d_in[19];
    const float* out1_b = (const float*)d_in[20];
    const float* out2_w = (const float*)d_in[21];
    const float* out2_b = (const float*)d_in[22];

    float* ws   = (float*)d_ws;
    float* nh   = ws;                   // 1024*256
    float* srcv = nh + 1024 * 256;      // 1024
    float* dstv = srcv + 1024;          // 1024
    float* nsv  = dstv + 1024;          // 1024
    float* msg  = nsv + 1024;           // 1024*3
    float* wpA  = msg + 1024 * 3;       // 128*4 (16B-aligned offset)
    float* wpB  = wpA + 512;            // 128*2

    k_node<<<256, 1024, 0, stream>>>(h, dl, temb, np1_w, np1_b, np2_w, np2_b,
                                     src_w, src_b, dst_w, dst_b, ns_w, ns_b,
                                     eg1_w, eg1_b, eg2_w,
                                     nh, srcv, dstv, nsv, wpA, wpB);
    k_edge<<<1024, 512, 0, stream>>>(x, fr, srcv, dstv, nsv, wpA, wpB, eg2_b, msg);
    k_out<<<256, 1024, 0, stream>>>(nh, dl, msg, out1_w, out1_b, out2_w, out2_b, (float*)d_out);
}